// Round 2
// baseline (967.360 us; speedup 1.0000x reference)
//
#include <hip/hip_runtime.h>
#include <math.h>

// ---- problem constants ----
#define T_TOK   16384
#define DMODEL  1024
#define DFF     4096
#define NEXP    8
#define CAPACITY 3277            // ceil(16384*1.6/8)
#define CAP_PAD  3328            // ceil(CAPACITY/256)*256 (also 26*128)

typedef unsigned short u16;
typedef __attribute__((ext_vector_type(8))) __bf16 bf16x8;
typedef __attribute__((ext_vector_type(4))) float  f32x4;

// ---- workspace layout (bytes). Total ~308 MiB. ----
#define W1T_OFF   0ull                         // 8*4096*1024*2 = 67108864   bf16 [E][DFF][D]  (B^T for GEMM1)
#define W2T_OFF   67108864ull                  // 67108864                   bf16 [E][D][DFF]  (B^T for GEMM2)
#define XG_OFF    134217728ull                 // 18432*1024*2 = 37748736    bf16 gathered x rows
#define H_OFF     171966464ull                 // 18432*4096*2 = 150994944   bf16 hidden
#define TOPK_OFF  322961408ull                 // 16384*2*4 = 131072
#define CCNT_OFF  323092480ull                 // 128*8*4
#define CBASE_OFF 323096576ull                 // 128*8*4
#define LISTS_OFF 323100672ull                 // 8*3328*4 = 106496
#define CNT_OFF   323207168ull                 // 8*4
#define OFFS_OFF  323207200ull                 // 9*4
#define PCNT_OFF  323207296ull                 // 8*4

__device__ __forceinline__ u16 f2bf(float x) {   // round-to-nearest-even f32->bf16
  union { float f; unsigned u; } v; v.f = x;
  unsigned r = v.u + 0x7fffu + ((v.u >> 16) & 1u);
  return (u16)(r >> 16);
}

__device__ __forceinline__ void async_cp16(const void* g, void* l) {
  // global -> LDS direct, 16B/lane. LDS dest is wave-uniform base + lane*16.
  __builtin_amdgcn_global_load_lds((const __attribute__((address_space(1))) void*)g,
                                   (__attribute__((address_space(3))) void*)l,
                                   16, 0, 0);
}

__device__ __forceinline__ void barrier_fence() {
  asm volatile("" ::: "memory");
  __builtin_amdgcn_s_barrier();
  asm volatile("" ::: "memory");
}

// ---- K1: fp32->bf16 transpose-convert, vectorized.  src [E][R][C] f32 -> dst [E][C][R] bf16 ----
__global__ __launch_bounds__(256) void transpose_cvt64(const float* __restrict__ src,
                                                       u16* __restrict__ dst, int R, int C) {
  int tilesC = C >> 6;
  int per_e = (R >> 6) * tilesC;
  int bid = blockIdx.x;
  int e = bid / per_e, rem = bid % per_e;
  int rt = rem / tilesC, ct = rem % tilesC;
  const float* s = src + (size_t)e * R * C;
  u16* d = dst + (size_t)e * R * C;
  __shared__ u16 tile[64][70];                 // pad 70: uniform bank spread
  int tid = threadIdx.x;
  int rr = tid >> 4;                           // 0..15
  int c4 = (tid & 15) << 2;                    // 0,4,..60
#pragma unroll
  for (int i = 0; i < 4; ++i) {
    int r = rr + i * 16;
    float4 v = *(const float4*)(s + (size_t)(rt*64 + r) * C + ct*64 + c4);
    tile[r][c4+0] = f2bf(v.x);
    tile[r][c4+1] = f2bf(v.y);
    tile[r][c4+2] = f2bf(v.z);
    tile[r][c4+3] = f2bf(v.w);
  }
  __syncthreads();
#pragma unroll
  for (int k = 0; k < 2; ++k) {
    int idx = k*256 + tid;
    int c  = idx >> 3;                         // 0..63 output row (C-dim)
    int rc = (idx & 7) << 3;                   // 0,8,..56
    union { u16 u[8]; uint4 v; } pk;
#pragma unroll
    for (int j = 0; j < 8; ++j) pk.u[j] = tile[rc + j][c];
    *(uint4*)(d + (size_t)(ct*64 + c) * R + rt*64 + rc) = pk.v;
  }
}

// ---- K2: router logits + noise, top-2 (fp64 accum to avoid near-tie flips) ----
__global__ __launch_bounds__(256) void router_topk(const float* __restrict__ x,
    const float* __restrict__ rw, const float* __restrict__ rb,
    const float* __restrict__ noise, int* __restrict__ topk) {
  int w = threadIdx.x >> 6, lane = threadIdx.x & 63;
  int t = blockIdx.x * 4 + w;
  const float* xr = x + (size_t)t * DMODEL;
  double acc[NEXP];
#pragma unroll
  for (int e = 0; e < NEXP; ++e) acc[e] = 0.0;
  for (int c = lane; c < DMODEL; c += 64) {
    float xv = xr[c];
#pragma unroll
    for (int e = 0; e < NEXP; ++e) acc[e] += (double)xv * (double)rw[e*DMODEL + c];
  }
#pragma unroll
  for (int e = 0; e < NEXP; ++e) {
#pragma unroll
    for (int off = 32; off > 0; off >>= 1) acc[e] += __shfl_down(acc[e], off, 64);
  }
  if (lane == 0) {
    double best = -1e300, sec = -1e300; int bi = 0, si = 0;
#pragma unroll
    for (int e = 0; e < NEXP; ++e) {
      double v = acc[e] + (double)rb[e] + (double)noise[(size_t)t*NEXP + e] * 0.02;
      if (v > best)     { sec = best; si = bi; best = v; bi = e; }
      else if (v > sec) { sec = v; si = e; }
    }
    topk[2*t] = bi; topk[2*t+1] = si;
  }
}

// ---- K3: per-128-token-chunk routed counts per expert ----
__global__ __launch_bounds__(128) void chunk_count(const int* __restrict__ topk,
                                                   int* __restrict__ ccnt) {
  int tid = threadIdx.x, lane = tid & 63, w = tid >> 6;
  int t = blockIdx.x*128 + tid;
  int i0 = topk[2*t], i1 = topk[2*t+1];
  __shared__ int cnt[2][NEXP];
#pragma unroll
  for (int e = 0; e < NEXP; ++e) {
    unsigned long long bal = __ballot((i0 == e) || (i1 == e));
    if (lane == 0) cnt[w][e] = __popcll(bal);
  }
  __syncthreads();
  if (tid < NEXP) ccnt[blockIdx.x*NEXP + tid] = cnt[0][tid] + cnt[1][tid];
}

// ---- K4: exclusive prefix of chunk counts (tiny) ----
__global__ void chunk_prefix(const int* __restrict__ ccnt, int* __restrict__ cbase) {
  int e = threadIdx.x;
  if (e < NEXP) {
    int run = 0;
    for (int c = 0; c < 128; ++c) { cbase[c*NEXP + e] = run; run += ccnt[c*NEXP + e]; }
  }
}

// ---- K5: capacity acceptance, final expert = max accepted, atomic compaction ----
__global__ __launch_bounds__(128) void assign_compact(const int* __restrict__ topk,
    const int* __restrict__ cbase, int* __restrict__ counts, int* __restrict__ lists) {
  int chunk = blockIdx.x, tid = threadIdx.x;
  int lane = tid & 63, w = tid >> 6;
  int t = chunk*128 + tid;
  int i0 = topk[2*t], i1 = topk[2*t+1];
  __shared__ int w0cnt[NEXP];
  unsigned long long below = (1ull << lane) - 1ull;
#pragma unroll
  for (int e = 0; e < NEXP; ++e) {
    unsigned long long bal = __ballot((i0 == e) || (i1 == e));
    if (w == 0 && lane == 0) w0cnt[e] = __popcll(bal);
  }
  __syncthreads();
  int fin = -1;
#pragma unroll
  for (int e = 0; e < NEXP; ++e) {
    bool m = (i0 == e) || (i1 == e);
    unsigned long long bal = __ballot(m);
    int rank = cbase[chunk*NEXP + e] + (w ? w0cnt[e] : 0) + __popcll(bal & below);
    if (m && rank < CAPACITY) fin = e;    // ascending e -> ends at max accepted
  }
#pragma unroll
  for (int e = 0; e < NEXP; ++e) {
    bool m = (fin == e);
    unsigned long long bal = __ballot(m);
    int c = __popcll(bal);
    if (c) {
      int leader = __ffsll((unsigned long long)bal) - 1;
      int base = 0;
      if (lane == leader) base = atomicAdd(&counts[e], c);
      base = __shfl(base, leader, 64);
      if (m) lists[e*CAP_PAD + base + __popcll(bal & below)] = t;
    }
  }
}

// ---- K6: padded counts (256-granular for 256-row M-tiles) + compact offsets ----
__global__ void calc_offsets(const int* __restrict__ counts, int* __restrict__ offs,
                             int* __restrict__ pcnt) {
  if (threadIdx.x == 0) {
    int run = 0;
    for (int e = 0; e < NEXP; ++e) {
      offs[e] = run;
      int pc = ((counts[e] + 255) >> 8) << 8;
      pcnt[e] = pc;
      run += pc;
    }
    offs[NEXP] = run;
  }
}

// ---- K7: gather x rows -> bf16 compact per-expert regions (pad rows zeroed) ----
__global__ __launch_bounds__(128) void gather_x(const float* __restrict__ x,
    const int* __restrict__ lists, const int* __restrict__ counts,
    const int* __restrict__ offs, const int* __restrict__ pcnt, u16* __restrict__ xg) {
  int bid = blockIdx.x;
  int e = bid / CAP_PAD, r = bid % CAP_PAD;
  if (r >= pcnt[e]) return;
  unsigned long long* dst = (unsigned long long*)(xg + (size_t)(offs[e] + r) * DMODEL);
  int tid = threadIdx.x;
  if (r < counts[e]) {
    const float4* src = (const float4*)(x + (size_t)lists[e*CAP_PAD + r] * DMODEL);
#pragma unroll
    for (int i = 0; i < 2; ++i) {
      float4 v = src[tid + i*128];
      unsigned long long pk = (unsigned long long)f2bf(v.x)
                            | ((unsigned long long)f2bf(v.y) << 16)
                            | ((unsigned long long)f2bf(v.z) << 32)
                            | ((unsigned long long)f2bf(v.w) << 48);
      dst[tid + i*128] = pk;
    }
  } else {
#pragma unroll
    for (int i = 0; i < 2; ++i) dst[tid + i*128] = 0ull;
  }
}

// ==================== 256x256 8-wave phase-pipelined GEMM ====================
// T2 swizzle: logical LDS byte (r*128 + cb) lives at r*128 + (cb ^ ((r&7)<<4)).
// Staged via pre-swizzled GLOBAL source, read with the same XOR (rule 21).
// T1: 1D grid, XCD-chunked bijective job swizzle. Since jobs/XCD == jobs/expert,
// each XCD owns exactly one expert; within-expert order = 4-nt groups, mt-major
// -> 32 co-resident blocks share 8 A-panels + 4 B-panels (~6 MB) in L2.

template<int S>  // row stride in elements (== K)
__device__ __forceinline__ void stage_half(const u16* __restrict__ g, int row0, int k0,
                                           u16* tile, int half, int tid) {
  int wid  = tid >> 6;
  int rloc = tid >> 3;                       // 0..63 row within this 64-row chunk
  int cb   = (tid & 7) << 4;                 // byte col 0..112 step 16
  int scb  = cb ^ ((rloc & 7) << 4);         // pre-swizzled source col (r&7 == rloc&7)
#pragma unroll
  for (int j = 0; j < 2; ++j) {
    int r = half*128 + j*64 + rloc;
    const u16* src = g + (size_t)(row0 + r) * S + k0 + (scb >> 1);
    u16* dst = tile + half*8192 + j*4096 + wid*512;   // u16 units; wave-uniform
    async_cp16(src, dst);
  }
}

__device__ __forceinline__ bf16x8 ldsfrag(const u16* tile, int r, int cb) {
  int a = r*128 + (cb ^ ((r & 7) << 4));     // byte offset, 16B aligned
  return *(const bf16x8*)((const char*)tile + a);
}

// EPI 0: h = gelu(xg@w1+b1) -> bf16 Hout.  EPI 1: out = h@w2+b2 -> f32 scatter.
template<int KELEM, int NTOT, int EPI>
__global__ __launch_bounds__(512, 2) void ffn_gemm8(
    const u16* __restrict__ Abase, const u16* __restrict__ Btall,
    const float* __restrict__ bias,
    const int* __restrict__ offs, const int* __restrict__ pcnt,
    const int* __restrict__ counts, const int* __restrict__ lists,
    u16* __restrict__ Hout, float* __restrict__ Fout) {
  constexpr int NKT = KELEM / 64;
  constexpr int NT_N = NTOT / 256;            // n-tiles per expert (16 or 4)
  constexpr int PER_E = 13 * NT_N;            // jobs per expert == jobs per XCD chunk
  // T1 bijective XCD swizzle: grid.x = 8*PER_E, block b runs on XCD b%8.
  int bid = blockIdx.x;
  int job = (bid & 7) * PER_E + (bid >> 3);   // XCD gets contiguous chunk
  int e = job / PER_E;                        // == bid & 7
  int local = job % PER_E;
  int g4  = local / 52;                       // 4-wide nt group
  int rem = local % 52;
  int mt = rem >> 2, nt = (g4 << 2) + (rem & 3);
  int pc = pcnt[e];
  int m0 = mt * 256;
  if (m0 >= pc) return;                       // uniform: before any barrier
  int n0 = nt * 256;
  int tid = threadIdx.x, lane = tid & 63, wid = tid >> 6;
  int wm = wid >> 2, wn = wid & 3;            // 2 x 4 waves; per-wave 128x64 output
  const u16* A = Abase + (size_t)offs[e] * KELEM;
  const u16* B = Btall + (size_t)e * NTOT * KELEM;
  __shared__ __align__(16) u16 lds[2][2][16384];  // [buf][A,B][32KB] = 128 KiB

  // Prologue: t0 fully into buf0; t1.B into buf1. 12 loads/thread in flight.
  stage_half<KELEM>(A, m0, 0,  (u16*)lds[0][0], 0, tid);
  stage_half<KELEM>(A, m0, 0,  (u16*)lds[0][0], 1, tid);
  stage_half<KELEM>(B, n0, 0,  (u16*)lds[0][1], 0, tid);
  stage_half<KELEM>(B, n0, 0,  (u16*)lds[0][1], 1, tid);
  stage_half<KELEM>(B, n0, 64, (u16*)lds[1][1], 0, tid);
  stage_half<KELEM>(B, n0, 64, (u16*)lds[1][1], 1, tid);
  asm volatile("s_waitcnt vmcnt(4)" ::: "memory");   // t0's 8 loads done; t1.B in flight
  barrier_fence();

  int frow = lane & 15;
  int fk   = (lane >> 4) << 4;                // k byte base within 64-col tile
  f32x4 acc[8][4] = {};

#pragma unroll 2
  for (int t = 0; t < NKT; ++t) {
    int cur = t & 1;
    u16* As_ = (u16*)lds[cur][0];
    u16* Bs_ = (u16*)lds[cur][1];
    u16* An_ = (u16*)lds[cur ^ 1][0];
    bf16x8 a[4][2], bb[2][2][2];

    // ---- phase 0: read A-low frags + B-low frags; stage t+1.A half0; MFMA Q00 ----
#pragma unroll
    for (int f = 0; f < 4; ++f)
#pragma unroll
      for (int kk = 0; kk < 2; ++kk)
        a[f][kk] = ldsfrag(As_, wm*128 + f*16 + frow, kk*64 + fk);
#pragma unroll
    for (int f = 0; f < 2; ++f)
#pragma unroll
      for (int kk = 0; kk < 2; ++kk)
        bb[0][f][kk] = ldsfrag(Bs_, wn*64 + f*16 + frow, kk*64 + fk);
    if (t + 1 < NKT) stage_half<KELEM>(A, m0, (t+1)*64, An_, 0, tid);
    barrier_fence();
    __builtin_amdgcn_s_setprio(1);
#pragma unroll
    for (int f = 0; f < 4; ++f)
#pragma unroll
      for (int g = 0; g < 2; ++g)
#pragma unroll
        for (int kk = 0; kk < 2; ++kk)
          acc[f][g] = __builtin_amdgcn_mfma_f32_16x16x32_bf16(a[f][kk], bb[0][g][kk], acc[f][g], 0, 0, 0);
    __builtin_amdgcn_s_setprio(0);
    barrier_fence();

    // ---- phase 1: read B-high frags; stage t+1.A half1; MFMA Q01 ----
#pragma unroll
    for (int f = 0; f < 2; ++f)
#pragma unroll
      for (int kk = 0; kk < 2; ++kk)
        bb[1][f][kk] = ldsfrag(Bs_, wn*64 + (2+f)*16 + frow, kk*64 + fk);
    if (t + 1 < NKT) stage_half<KELEM>(A, m0, (t+1)*64, An_, 1, tid);
    barrier_fence();
    __builtin_amdgcn_s_setprio(1);
#pragma unroll
    for (int f = 0; f < 4; ++f)
#pragma unroll
      for (int g = 0; g < 2; ++g)
#pragma unroll
        for (int kk = 0; kk < 2; ++kk)
          acc[f][2+g] = __builtin_amdgcn_mfma_f32_16x16x32_bf16(a[f][kk], bb[1][g][kk], acc[f][2+g], 0, 0, 0);
    __builtin_amdgcn_s_setprio(0);
    barrier_fence();

    // ---- phase 2: read A-high frags; stage t+2.B half0 into cur.B; MFMA Q10 ----
#pragma unroll
    for (int f = 0; f < 4; ++f)
#pragma unroll
      for (int kk = 0; kk < 2; ++kk)
        a[f][kk] = ldsfrag(As_, wm*128 + 64 + f*16 + frow, kk*64 + fk);
    if (t + 2 < NKT) stage_half<KELEM>(B, n0, (t+2)*64, Bs_, 0, tid);
    barrier_fence();
    __builtin_amdgcn_s_setprio(1);
#pragma unroll
    for (int f = 0; f < 4; ++f)
#pragma unroll
      for (int g = 0; g < 2; ++g)
#pragma unroll
        for (int kk = 0; kk < 2; ++kk)
          acc[4+f][g] = __builtin_amdgcn_mfma_f32_16x16x32_bf16(a[f][kk], bb[0][g][kk], acc[4+f][g], 0, 0, 0);
    __builtin_amdgcn_s_setprio(0);
    barrier_fence();

    // ---- phase 3: stage t+2.B half1; MFMA Q11; counted boundary vmcnt; barrier ----
    if (t + 2 < NKT) stage_half<KELEM>(B, n0, (t+2)*64, Bs_, 1, tid);
    barrier_fence();
    __builtin_amdgcn_s_setprio(1);
#pragma unroll
    for (int f = 0; f < 4; ++f)
#pragma unroll
      for (int g = 0; g < 2; ++g)
#pragma unroll
        for (int kk = 0; kk < 2; ++kk)
          acc[4+f][2+g] = __builtin_amdgcn_mfma_f32_16x16x32_bf16(a[f][kk], bb[1][g][kk], acc[4+f][2+g], 0, 0, 0);
    __builtin_amdgcn_s_setprio(0);
    // Boundary wait for tile t+1: oldest 8 of 12 in-flight loads are t+1's 4 halves.
    if (t + 2 < NKT)      asm volatile("s_waitcnt vmcnt(4)" ::: "memory");
    else if (t + 1 < NKT) asm volatile("s_waitcnt vmcnt(0)" ::: "memory");  // epilogue drain
    barrier_fence();
  }

  // ---- epilogue ----
  if constexpr (EPI == 0) {
    // Vectorized H write: repack each wave's 16x64 bf16 sub-tile through a
    // private LDS region (rows padded to 72 u16), then 16B stores (full lines).
    const float* be = bias + e * NTOT;
    u16* H = Hout + (size_t)offs[e] * NTOT;
    u16* mybuf = ((u16*)lds) + wid * 1280;     // 16*72=1152 u16 used, pad to 1280
    float bv[4];
#pragma unroll
    for (int g = 0; g < 4; ++g) bv[g] = be[n0 + wn*64 + g*16 + frow];
    int r4 = (lane >> 4) * 4;
#pragma unroll
    for (int f = 0; f < 8; ++f) {
#pragma unroll
      for (int g = 0; g < 4; ++g)
#pragma unroll
        for (int r = 0; r < 4; ++r) {
          float v = acc[f][g][r] + bv[g];
          float gl = 0.5f * v * (1.0f + erff(v * 0.70710678118654752f));  // exact gelu
          mybuf[(r4 + r) * 72 + g*16 + frow] = f2bf(gl);
        }
      asm volatile("s_waitcnt lgkmcnt(0)" ::: "memory");   // wave-local write->read
#pragma unroll
      for (int rr = 0; rr < 2; ++rr) {
        int row = (lane >> 3) + rr*8;
        int cb  = lane & 7;
        bf16x8 vv = *(const bf16x8*)(mybuf + row*72 + cb*8);
        *(bf16x8*)(H + (size_t)(m0 + wm*128 + f*16 + row) * NTOT + n0 + wn*64 + cb*8) = vv;
      }
      asm volatile("s_waitcnt lgkmcnt(0)" ::: "memory");   // reads done before next f
    }
  } else {
    int cnt = counts[e];
    const float* be = bias + e * NTOT;
    const int* le = lists + e * CAP_PAD;
#pragma unroll
    for (int g = 0; g < 4; ++g) {
      int col = n0 + wn*64 + g*16 + frow;
      float bvs = be[col];
#pragma unroll
      for (int f = 0; f < 8; ++f)
#pragma unroll
        for (int r = 0; r < 4; ++r) {
          int row = m0 + wm*128 + f*16 + (lane >> 4)*4 + r;
          if (row < cnt) {
            int tk = le[row];
            Fout[(size_t)tk * DMODEL + col] = acc[f][g][r] + bvs;
          }
        }
    }
  }
}

extern "C" void kernel_launch(void* const* d_in, const int* in_sizes, int n_in,
                              void* d_out, int out_size, void* d_ws, size_t ws_size,
                              hipStream_t stream) {
  const float* x     = (const float*)d_in[0];
  const float* noise = (const float*)d_in[1];
  const float* rw    = (const float*)d_in[2];
  const float* rb    = (const float*)d_in[3];
  const float* w1    = (const float*)d_in[4];
  const float* b1    = (const float*)d_in[5];
  const float* w2    = (const float*)d_in[6];
  const float* b2    = (const float*)d_in[7];
  float* out = (float*)d_out;
  char* ws = (char*)d_ws;

  u16* w1t   = (u16*)(ws + W1T_OFF);
  u16* w2t   = (u16*)(ws + W2T_OFF);
  u16* xg    = (u16*)(ws + XG_OFF);
  u16* hbuf  = (u16*)(ws + H_OFF);
  int* topk  = (int*)(ws + TOPK_OFF);
  int* ccnt  = (int*)(ws + CCNT_OFF);
  int* cbase = (int*)(ws + CBASE_OFF);
  int* lists = (int*)(ws + LISTS_OFF);
  int* cnts  = (int*)(ws + CNT_OFF);
  int* offs  = (int*)(ws + OFFS_OFF);
  int* pcnt  = (int*)(ws + PCNT_OFF);

  // unassigned tokens must be zero; counts must start at zero
  hipMemsetAsync(d_out, 0, (size_t)T_TOK * DMODEL * sizeof(float), stream);
  hipMemsetAsync(cnts, 0, NEXP * sizeof(int), stream);

  transpose_cvt64<<<NEXP*(DMODEL/64)*(DFF/64), 256, 0, stream>>>(w1, w1t, DMODEL, DFF);
  transpose_cvt64<<<NEXP*(DFF/64)*(DMODEL/64), 256, 0, stream>>>(w2, w2t, DFF, DMODEL);
  router_topk<<<T_TOK/4, 256, 0, stream>>>(x, rw, rb, noise, topk);
  chunk_count<<<128, 128, 0, stream>>>(topk, ccnt);
  chunk_prefix<<<1, 64, 0, stream>>>(ccnt, cbase);
  assign_compact<<<128, 128, 0, stream>>>(topk, cbase, cnts, lists);
  calc_offsets<<<1, 64, 0, stream>>>(cnts, offs, pcnt);
  gather_x<<<NEXP*CAP_PAD, 128, 0, stream>>>(x, lists, cnts, offs, pcnt, xg);
  ffn_gemm8<DMODEL, DFF, 0><<<NEXP*13*(DFF/256), 512, 0, stream>>>(
      xg, w1t, b1, offs, pcnt, cnts, lists, hbuf, nullptr);
  ffn_gemm8<DFF, DMODEL, 1><<<NEXP*13*(DMODEL/256), 512, 0, stream>>>(
      hbuf, w2t, b2, offs, pcnt, cnts, lists, nullptr, out);
}

// Round 4
// 745.900 us; speedup vs baseline: 1.2969x; 1.2969x over previous
//
#include <hip/hip_runtime.h>
#include <math.h>

// ---- problem constants ----
#define T_TOK   16384
#define DMODEL  1024
#define DFF     4096
#define NEXP    8
#define CAPACITY 3277            // ceil(16384*1.6/8)
#define CAP_PAD  3328            // ceil(CAPACITY/256)*256 (also 26*128)

typedef unsigned short u16;
typedef __attribute__((ext_vector_type(8))) __bf16 bf16x8;
typedef __attribute__((ext_vector_type(4))) float  f32x4;

// ---- workspace layout (bytes). Total ~308 MiB. ----
#define W1T_OFF   0ull                         // 8*4096*1024*2 = 67108864   bf16 [E][DFF][D]  (B^T for GEMM1)
#define W2T_OFF   67108864ull                  // 67108864                   bf16 [E][D][DFF]  (B^T for GEMM2)
#define XG_OFF    134217728ull                 // 18432*1024*2 = 37748736    bf16 gathered x rows
#define H_OFF     171966464ull                 // 18432*4096*2 = 150994944   bf16 hidden
#define TOPK_OFF  322961408ull                 // 16384*2*4 = 131072
#define CCNT_OFF  323092480ull                 // 128*8*4
#define CBASE_OFF 323096576ull                 // 128*8*4
#define LISTS_OFF 323100672ull                 // 8*3328*4 = 106496
#define CNT_OFF   323207168ull                 // 8*4
#define OFFS_OFF  323207200ull                 // 9*4
#define PCNT_OFF  323207296ull                 // 8*4

__device__ __forceinline__ u16 f2bf(float x) {   // round-to-nearest-even f32->bf16
  union { float f; unsigned u; } v; v.f = x;
  unsigned r = v.u + 0x7fffu + ((v.u >> 16) & 1u);
  return (u16)(r >> 16);
}

__device__ __forceinline__ void async_cp16(const void* g, void* l) {
  // global -> LDS direct, 16B/lane. LDS dest is wave-uniform base + lane*16.
  __builtin_amdgcn_global_load_lds((const __attribute__((address_space(1))) void*)g,
                                   (__attribute__((address_space(3))) void*)l,
                                   16, 0, 0);
}

__device__ __forceinline__ void barrier_fence() {
  asm volatile("" ::: "memory");
  __builtin_amdgcn_s_barrier();
  asm volatile("" ::: "memory");
}

// ---- K1: fp32->bf16 transpose-convert, vectorized.  src [E][R][C] f32 -> dst [E][C][R] bf16 ----
__global__ __launch_bounds__(256) void transpose_cvt64(const float* __restrict__ src,
                                                       u16* __restrict__ dst, int R, int C) {
  int tilesC = C >> 6;
  int per_e = (R >> 6) * tilesC;
  int bid = blockIdx.x;
  int e = bid / per_e, rem = bid % per_e;
  int rt = rem / tilesC, ct = rem % tilesC;
  const float* s = src + (size_t)e * R * C;
  u16* d = dst + (size_t)e * R * C;
  __shared__ u16 tile[64][70];                 // pad 70: uniform bank spread
  int tid = threadIdx.x;
  int rr = tid >> 4;                           // 0..15
  int c4 = (tid & 15) << 2;                    // 0,4,..60
#pragma unroll
  for (int i = 0; i < 4; ++i) {
    int r = rr + i * 16;
    float4 v = *(const float4*)(s + (size_t)(rt*64 + r) * C + ct*64 + c4);
    tile[r][c4+0] = f2bf(v.x);
    tile[r][c4+1] = f2bf(v.y);
    tile[r][c4+2] = f2bf(v.z);
    tile[r][c4+3] = f2bf(v.w);
  }
  __syncthreads();
#pragma unroll
  for (int k = 0; k < 2; ++k) {
    int idx = k*256 + tid;
    int c  = idx >> 3;                         // 0..63 output row (C-dim)
    int rc = (idx & 7) << 3;                   // 0,8,..56
    union { u16 u[8]; uint4 v; } pk;
#pragma unroll
    for (int j = 0; j < 8; ++j) pk.u[j] = tile[rc + j][c];
    *(uint4*)(d + (size_t)(ct*64 + c) * R + rt*64 + rc) = pk.v;
  }
}

// ---- K2: router logits + noise, top-2 (fp64 accum to avoid near-tie flips) ----
__global__ __launch_bounds__(256) void router_topk(const float* __restrict__ x,
    const float* __restrict__ rw, const float* __restrict__ rb,
    const float* __restrict__ noise, int* __restrict__ topk) {
  int w = threadIdx.x >> 6, lane = threadIdx.x & 63;
  int t = blockIdx.x * 4 + w;
  const float* xr = x + (size_t)t * DMODEL;
  double acc[NEXP];
#pragma unroll
  for (int e = 0; e < NEXP; ++e) acc[e] = 0.0;
  for (int c = lane; c < DMODEL; c += 64) {
    float xv = xr[c];
#pragma unroll
    for (int e = 0; e < NEXP; ++e) acc[e] += (double)xv * (double)rw[e*DMODEL + c];
  }
#pragma unroll
  for (int e = 0; e < NEXP; ++e) {
#pragma unroll
    for (int off = 32; off > 0; off >>= 1) acc[e] += __shfl_down(acc[e], off, 64);
  }
  if (lane == 0) {
    double best = -1e300, sec = -1e300; int bi = 0, si = 0;
#pragma unroll
    for (int e = 0; e < NEXP; ++e) {
      double v = acc[e] + (double)rb[e] + (double)noise[(size_t)t*NEXP + e] * 0.02;
      if (v > best)     { sec = best; si = bi; best = v; bi = e; }
      else if (v > sec) { sec = v; si = e; }
    }
    topk[2*t] = bi; topk[2*t+1] = si;
  }
}

// ---- K3: per-128-token-chunk routed counts per expert ----
__global__ __launch_bounds__(128) void chunk_count(const int* __restrict__ topk,
                                                   int* __restrict__ ccnt) {
  int tid = threadIdx.x, lane = tid & 63, w = tid >> 6;
  int t = blockIdx.x*128 + tid;
  int i0 = topk[2*t], i1 = topk[2*t+1];
  __shared__ int cnt[2][NEXP];
#pragma unroll
  for (int e = 0; e < NEXP; ++e) {
    unsigned long long bal = __ballot((i0 == e) || (i1 == e));
    if (lane == 0) cnt[w][e] = __popcll(bal);
  }
  __syncthreads();
  if (tid < NEXP) ccnt[blockIdx.x*NEXP + tid] = cnt[0][tid] + cnt[1][tid];
}

// ---- K4: exclusive prefix of chunk counts (tiny) ----
__global__ void chunk_prefix(const int* __restrict__ ccnt, int* __restrict__ cbase) {
  int e = threadIdx.x;
  if (e < NEXP) {
    int run = 0;
    for (int c = 0; c < 128; ++c) { cbase[c*NEXP + e] = run; run += ccnt[c*NEXP + e]; }
  }
}

// ---- K5: capacity acceptance, final expert = max accepted, atomic compaction ----
__global__ __launch_bounds__(128) void assign_compact(const int* __restrict__ topk,
    const int* __restrict__ cbase, int* __restrict__ counts, int* __restrict__ lists) {
  int chunk = blockIdx.x, tid = threadIdx.x;
  int lane = tid & 63, w = tid >> 6;
  int t = chunk*128 + tid;
  int i0 = topk[2*t], i1 = topk[2*t+1];
  __shared__ int w0cnt[NEXP];
  unsigned long long below = (1ull << lane) - 1ull;
#pragma unroll
  for (int e = 0; e < NEXP; ++e) {
    unsigned long long bal = __ballot((i0 == e) || (i1 == e));
    if (w == 0 && lane == 0) w0cnt[e] = __popcll(bal);
  }
  __syncthreads();
  int fin = -1;
#pragma unroll
  for (int e = 0; e < NEXP; ++e) {
    bool m = (i0 == e) || (i1 == e);
    unsigned long long bal = __ballot(m);
    int rank = cbase[chunk*NEXP + e] + (w ? w0cnt[e] : 0) + __popcll(bal & below);
    if (m && rank < CAPACITY) fin = e;    // ascending e -> ends at max accepted
  }
#pragma unroll
  for (int e = 0; e < NEXP; ++e) {
    bool m = (fin == e);
    unsigned long long bal = __ballot(m);
    int c = __popcll(bal);
    if (c) {
      int leader = __ffsll((unsigned long long)bal) - 1;
      int base = 0;
      if (lane == leader) base = atomicAdd(&counts[e], c);
      base = __shfl(base, leader, 64);
      if (m) lists[e*CAP_PAD + base + __popcll(bal & below)] = t;
    }
  }
}

// ---- K6: padded counts (256-granular for 256-row M-tiles) + compact offsets ----
__global__ void calc_offsets(const int* __restrict__ counts, int* __restrict__ offs,
                             int* __restrict__ pcnt) {
  if (threadIdx.x == 0) {
    int run = 0;
    for (int e = 0; e < NEXP; ++e) {
      offs[e] = run;
      int pc = ((counts[e] + 255) >> 8) << 8;
      pcnt[e] = pc;
      run += pc;
    }
    offs[NEXP] = run;
  }
}

// ---- K7: gather x rows -> bf16 compact per-expert regions (pad rows zeroed) ----
__global__ __launch_bounds__(128) void gather_x(const float* __restrict__ x,
    const int* __restrict__ lists, const int* __restrict__ counts,
    const int* __restrict__ offs, const int* __restrict__ pcnt, u16* __restrict__ xg) {
  int bid = blockIdx.x;
  int e = bid / CAP_PAD, r = bid % CAP_PAD;
  if (r >= pcnt[e]) return;
  unsigned long long* dst = (unsigned long long*)(xg + (size_t)(offs[e] + r) * DMODEL);
  int tid = threadIdx.x;
  if (r < counts[e]) {
    const float4* src = (const float4*)(x + (size_t)lists[e*CAP_PAD + r] * DMODEL);
#pragma unroll
    for (int i = 0; i < 2; ++i) {
      float4 v = src[tid + i*128];
      unsigned long long pk = (unsigned long long)f2bf(v.x)
                            | ((unsigned long long)f2bf(v.y) << 16)
                            | ((unsigned long long)f2bf(v.z) << 32)
                            | ((unsigned long long)f2bf(v.w) << 48);
      dst[tid + i*128] = pk;
    }
  } else {
#pragma unroll
    for (int i = 0; i < 2; ++i) dst[tid + i*128] = 0ull;
  }
}

// ==================== 256x256 8-wave phase-pipelined GEMM ====================
// T2 swizzle: logical LDS byte (r*128 + cb) lives at r*128 + (cb ^ ((r&7)<<4)).
// Staged via pre-swizzled GLOBAL source, read with the same XOR (rule 21).
// Grid: 3D (x=nt fastest, y=mt, z=e) — interleaves experts across XCDs for
// load balance (R2 lesson: expert-per-XCD chunking halves occupancy on skewed
// counts); consecutive nt blocks share the A panel for L2 reuse.

template<int S>  // row stride in elements (== K)
__device__ __forceinline__ void stage_half(const u16* __restrict__ g, int row0, int k0,
                                           u16* tile, int half, int tid) {
  int wid  = tid >> 6;
  int rloc = tid >> 3;                       // 0..63 row within this 64-row chunk
  int cb   = (tid & 7) << 4;                 // byte col 0..112 step 16
  int scb  = cb ^ ((rloc & 7) << 4);         // pre-swizzled source col (r&7 == rloc&7)
#pragma unroll
  for (int j = 0; j < 2; ++j) {
    int r = half*128 + j*64 + rloc;
    const u16* src = g + (size_t)(row0 + r) * S + k0 + (scb >> 1);
    u16* dst = tile + half*8192 + j*4096 + wid*512;   // u16 units; wave-uniform
    async_cp16(src, dst);
  }
}

__device__ __forceinline__ bf16x8 ldsfrag(const u16* tile, int r, int cb) {
  int a = r*128 + (cb ^ ((r & 7) << 4));     // byte offset, 16B aligned
  return *(const bf16x8*)((const char*)tile + a);
}

// EPI 0: h = gelu(xg@w1+b1) -> bf16 Hout.  EPI 1: out = h@w2+b2 -> f32 scatter.
template<int KELEM, int NTOT, int EPI>
__global__ __launch_bounds__(512, 2) void ffn_gemm8(
    const u16* __restrict__ Abase, const u16* __restrict__ Btall,
    const float* __restrict__ bias,
    const int* __restrict__ offs, const int* __restrict__ pcnt,
    const int* __restrict__ counts, const int* __restrict__ lists,
    u16* __restrict__ Hout, float* __restrict__ Fout) {
  constexpr int NKT = KELEM / 64;
  int e = blockIdx.z, mt = blockIdx.y, nt = blockIdx.x;
  int pc = pcnt[e];
  int m0 = mt * 256;
  if (m0 >= pc) return;                       // uniform: before any barrier
  int n0 = nt * 256;
  int tid = threadIdx.x, lane = tid & 63, wid = tid >> 6;
  int wm = wid >> 2, wn = wid & 3;            // 2 x 4 waves; per-wave 128x64 output
  const u16* A = Abase + (size_t)offs[e] * KELEM;
  const u16* B = Btall + (size_t)e * NTOT * KELEM;
  __shared__ __align__(16) u16 lds[2][2][16384];  // [buf][A,B][32KB] = 128 KiB

  // Prologue: t0 fully into buf0; t1.B into buf1. 12 loads/thread in flight.
  stage_half<KELEM>(A, m0, 0,  (u16*)lds[0][0], 0, tid);
  stage_half<KELEM>(A, m0, 0,  (u16*)lds[0][0], 1, tid);
  stage_half<KELEM>(B, n0, 0,  (u16*)lds[0][1], 0, tid);
  stage_half<KELEM>(B, n0, 0,  (u16*)lds[0][1], 1, tid);
  stage_half<KELEM>(B, n0, 64, (u16*)lds[1][1], 0, tid);
  stage_half<KELEM>(B, n0, 64, (u16*)lds[1][1], 1, tid);
  asm volatile("s_waitcnt vmcnt(4)" ::: "memory");   // t0's 8 loads done; t1.B in flight
  barrier_fence();

  int frow = lane & 15;
  int fk   = (lane >> 4) << 4;                // k byte base within 64-col tile
  f32x4 acc[8][4] = {};

#pragma unroll 2
  for (int t = 0; t < NKT; ++t) {
    int cur = t & 1;
    u16* As_ = (u16*)lds[cur][0];
    u16* Bs_ = (u16*)lds[cur][1];
    u16* An_ = (u16*)lds[cur ^ 1][0];
    bf16x8 a[4][2], bb[2][2][2];

    // ---- phase 0: read A-low frags + B-low frags; stage t+1.A half0; MFMA Q00 ----
#pragma unroll
    for (int f = 0; f < 4; ++f)
#pragma unroll
      for (int kk = 0; kk < 2; ++kk)
        a[f][kk] = ldsfrag(As_, wm*128 + f*16 + frow, kk*64 + fk);
#pragma unroll
    for (int f = 0; f < 2; ++f)
#pragma unroll
      for (int kk = 0; kk < 2; ++kk)
        bb[0][f][kk] = ldsfrag(Bs_, wn*64 + f*16 + frow, kk*64 + fk);
    if (t + 1 < NKT) stage_half<KELEM>(A, m0, (t+1)*64, An_, 0, tid);
    barrier_fence();
    __builtin_amdgcn_s_setprio(1);
#pragma unroll
    for (int f = 0; f < 4; ++f)
#pragma unroll
      for (int g = 0; g < 2; ++g)
#pragma unroll
        for (int kk = 0; kk < 2; ++kk)
          acc[f][g] = __builtin_amdgcn_mfma_f32_16x16x32_bf16(a[f][kk], bb[0][g][kk], acc[f][g], 0, 0, 0);
    __builtin_amdgcn_s_setprio(0);
    barrier_fence();

    // ---- phase 1: read B-high frags; stage t+1.A half1; MFMA Q01 ----
#pragma unroll
    for (int f = 0; f < 2; ++f)
#pragma unroll
      for (int kk = 0; kk < 2; ++kk)
        bb[1][f][kk] = ldsfrag(Bs_, wn*64 + (2+f)*16 + frow, kk*64 + fk);
    if (t + 1 < NKT) stage_half<KELEM>(A, m0, (t+1)*64, An_, 1, tid);
    barrier_fence();
    __builtin_amdgcn_s_setprio(1);
#pragma unroll
    for (int f = 0; f < 4; ++f)
#pragma unroll
      for (int g = 0; g < 2; ++g)
#pragma unroll
        for (int kk = 0; kk < 2; ++kk)
          acc[f][2+g] = __builtin_amdgcn_mfma_f32_16x16x32_bf16(a[f][kk], bb[1][g][kk], acc[f][2+g], 0, 0, 0);
    __builtin_amdgcn_s_setprio(0);
    barrier_fence();

    // ---- phase 2: read A-high frags; stage t+2.B half0 into cur.B; MFMA Q10 ----
#pragma unroll
    for (int f = 0; f < 4; ++f)
#pragma unroll
      for (int kk = 0; kk < 2; ++kk)
        a[f][kk] = ldsfrag(As_, wm*128 + 64 + f*16 + frow, kk*64 + fk);
    if (t + 2 < NKT) stage_half<KELEM>(B, n0, (t+2)*64, Bs_, 0, tid);
    barrier_fence();
    __builtin_amdgcn_s_setprio(1);
#pragma unroll
    for (int f = 0; f < 4; ++f)
#pragma unroll
      for (int g = 0; g < 2; ++g)
#pragma unroll
        for (int kk = 0; kk < 2; ++kk)
          acc[4+f][g] = __builtin_amdgcn_mfma_f32_16x16x32_bf16(a[f][kk], bb[0][g][kk], acc[4+f][g], 0, 0, 0);
    __builtin_amdgcn_s_setprio(0);
    barrier_fence();

    // ---- phase 3: stage t+2.B half1; MFMA Q11; counted boundary vmcnt; barrier ----
    if (t + 2 < NKT) stage_half<KELEM>(B, n0, (t+2)*64, Bs_, 1, tid);
    barrier_fence();
    __builtin_amdgcn_s_setprio(1);
#pragma unroll
    for (int f = 0; f < 4; ++f)
#pragma unroll
      for (int g = 0; g < 2; ++g)
#pragma unroll
        for (int kk = 0; kk < 2; ++kk)
          acc[4+f][2+g] = __builtin_amdgcn_mfma_f32_16x16x32_bf16(a[f][kk], bb[1][g][kk], acc[4+f][2+g], 0, 0, 0);
    __builtin_amdgcn_s_setprio(0);
    // Boundary wait for tile t+1: oldest 8 of 12 in-flight loads are t+1's 4 halves.
    if (t + 2 < NKT)      asm volatile("s_waitcnt vmcnt(4)" ::: "memory");
    else if (t + 1 < NKT) asm volatile("s_waitcnt vmcnt(0)" ::: "memory");  // epilogue drain
    barrier_fence();
  }

  // ---- epilogue ----
  if constexpr (EPI == 0) {
    // Vectorized H write: repack each wave's 16x64 bf16 sub-tile through a
    // private LDS region (rows padded to 72 u16), then 16B stores (full lines).
    const float* be = bias + e * NTOT;
    u16* H = Hout + (size_t)offs[e] * NTOT;
    u16* mybuf = ((u16*)lds) + wid * 1280;     // 16*72=1152 u16 used, pad to 1280
    float bv[4];
#pragma unroll
    for (int g = 0; g < 4; ++g) bv[g] = be[n0 + wn*64 + g*16 + frow];
    int r4 = (lane >> 4) * 4;
#pragma unroll
    for (int f = 0; f < 8; ++f) {
#pragma unroll
      for (int g = 0; g < 4; ++g)
#pragma unroll
        for (int r = 0; r < 4; ++r) {
          float v = acc[f][g][r] + bv[g];
          float gl = 0.5f * v * (1.0f + erff(v * 0.70710678118654752f));  // exact gelu
          mybuf[(r4 + r) * 72 + g*16 + frow] = f2bf(gl);
        }
      asm volatile("s_waitcnt lgkmcnt(0)" ::: "memory");   // wave-local write->read
#pragma unroll
      for (int rr = 0; rr < 2; ++rr) {
        int row = (lane >> 3) + rr*8;
        int cb  = lane & 7;
        bf16x8 vv = *(const bf16x8*)(mybuf + row*72 + cb*8);
        *(bf16x8*)(H + (size_t)(m0 + wm*128 + f*16 + row) * NTOT + n0 + wn*64 + cb*8) = vv;
      }
      asm volatile("s_waitcnt lgkmcnt(0)" ::: "memory");   // reads done before next f
    }
  } else {
    // Vectorized scatter: repack each wave's 16x64 f32 sub-tile (bias added)
    // through private LDS, then 4x f32x4 (16B) stores per lane to the token row.
    int cnt = counts[e];
    const float* be = bias + e * NTOT;
    const int* le = lists + e * CAP_PAD;
    float* mybuf = (float*)((u16*)lds + wid * 2304);   // 16*68=1088 f32, pad 1152 f32
    float bv[4];
#pragma unroll
    for (int g = 0; g < 4; ++g) bv[g] = be[n0 + wn*64 + g*16 + frow];
    int r4 = (lane >> 4) * 4;
#pragma unroll
    for (int f = 0; f < 8; ++f) {
#pragma unroll
      for (int g = 0; g < 4; ++g)
#pragma unroll
        for (int r = 0; r < 4; ++r)
          mybuf[(r4 + r) * 68 + g*16 + frow] = acc[f][g][r] + bv[g];
      asm volatile("s_waitcnt lgkmcnt(0)" ::: "memory");   // wave-local write->read
      int row = lane >> 2, cg = lane & 3;                  // 16 rows x 4 col-groups
      int grow = m0 + wm*128 + f*16 + row;
      if (grow < cnt) {
        int tk = le[grow];
        float* po = Fout + (size_t)tk * DMODEL + n0 + wn*64 + cg*16;
        const float* pb = mybuf + row*68 + cg*16;
#pragma unroll
        for (int j = 0; j < 4; ++j)
          *(f32x4*)(po + j*4) = *(const f32x4*)(pb + j*4);
      }
      asm volatile("s_waitcnt lgkmcnt(0)" ::: "memory");   // reads done before next f
    }
  }
}

extern "C" void kernel_launch(void* const* d_in, const int* in_sizes, int n_in,
                              void* d_out, int out_size, void* d_ws, size_t ws_size,
                              hipStream_t stream) {
  const float* x     = (const float*)d_in[0];
  const float* noise = (const float*)d_in[1];
  const float* rw    = (const float*)d_in[2];
  const float* rb    = (const float*)d_in[3];
  const float* w1    = (const float*)d_in[4];
  const float* b1    = (const float*)d_in[5];
  const float* w2    = (const float*)d_in[6];
  const float* b2    = (const float*)d_in[7];
  float* out = (float*)d_out;
  char* ws = (char*)d_ws;

  u16* w1t   = (u16*)(ws + W1T_OFF);
  u16* w2t   = (u16*)(ws + W2T_OFF);
  u16* xg    = (u16*)(ws + XG_OFF);
  u16* hbuf  = (u16*)(ws + H_OFF);
  int* topk  = (int*)(ws + TOPK_OFF);
  int* ccnt  = (int*)(ws + CCNT_OFF);
  int* cbase = (int*)(ws + CBASE_OFF);
  int* lists = (int*)(ws + LISTS_OFF);
  int* cnts  = (int*)(ws + CNT_OFF);
  int* offs  = (int*)(ws + OFFS_OFF);
  int* pcnt  = (int*)(ws + PCNT_OFF);

  // unassigned tokens must be zero; counts must start at zero
  hipMemsetAsync(d_out, 0, (size_t)T_TOK * DMODEL * sizeof(float), stream);
  hipMemsetAsync(cnts, 0, NEXP * sizeof(int), stream);

  transpose_cvt64<<<NEXP*(DMODEL/64)*(DFF/64), 256, 0, stream>>>(w1, w1t, DMODEL, DFF);
  transpose_cvt64<<<NEXP*(DFF/64)*(DMODEL/64), 256, 0, stream>>>(w2, w2t, DFF, DMODEL);
  router_topk<<<T_TOK/4, 256, 0, stream>>>(x, rw, rb, noise, topk);
  chunk_count<<<128, 128, 0, stream>>>(topk, ccnt);
  chunk_prefix<<<1, 64, 0, stream>>>(ccnt, cbase);
  assign_compact<<<128, 128, 0, stream>>>(topk, cbase, cnts, lists);
  calc_offsets<<<1, 64, 0, stream>>>(cnts, offs, pcnt);
  gather_x<<<NEXP*CAP_PAD, 128, 0, stream>>>(x, lists, cnts, offs, pcnt, xg);
  ffn_gemm8<DMODEL, DFF, 0><<<dim3(DFF/256, CAP_PAD/256, NEXP), 512, 0, stream>>>(
      xg, w1t, b1, offs, pcnt, cnts, lists, hbuf, nullptr);
  ffn_gemm8<DFF, DMODEL, 1><<<dim3(DMODEL/256, CAP_PAD/256, NEXP), 512, 0, stream>>>(
      hbuf, w2t, b2, offs, pcnt, cnts, lists, nullptr, out);
}

// Round 5
// 726.421 us; speedup vs baseline: 1.3317x; 1.0268x over previous
//
#include <hip/hip_runtime.h>
#include <math.h>

// ---- problem constants ----
#define T_TOK   16384
#define DMODEL  1024
#define DFF     4096
#define NEXP    8
#define CAPACITY 3277            // ceil(16384*1.6/8)
#define CAP_PAD  3328            // ceil(CAPACITY/256)*256 (also 26*128)

typedef unsigned short u16;
typedef __attribute__((ext_vector_type(8))) __bf16 bf16x8;
typedef __attribute__((ext_vector_type(4))) float  f32x4;

// ---- workspace layout (bytes). Total ~323.3 MiB. ----
#define W1T_OFF   0ull                         // 8*4096*1024*2 = 67108864   bf16 [E][DFF][D]  (B^T for GEMM1)
#define W2T_OFF   67108864ull                  // 67108864                   bf16 [E][D][DFF]  (B^T for GEMM2)
#define XG_OFF    134217728ull                 // 18432*1024*2 = 37748736    bf16 gathered x rows
#define H_OFF     171966464ull                 // 18432*4096*2 = 150994944   bf16 hidden
#define TOPK_OFF  322961408ull                 // 16384*2*4 = 131072
#define CCNT_OFF  323092480ull                 // 128*8*4
#define CBASE_OFF 323096576ull                 // 128*8*4
#define LISTS_OFF 323100672ull                 // 8*3328*4 = 106496
#define CNT_OFF   323207168ull                 // 8*4
#define OFFS_OFF  323207200ull                 // 9*4
#define PCNT_OFF  323207296ull                 // 8*4
#define ACC_OFF   323207424ull                 // 16384*4 = 65536 accept flags

__device__ __forceinline__ u16 f2bf(float x) {   // round-to-nearest-even f32->bf16
  union { float f; unsigned u; } v; v.f = x;
  unsigned r = v.u + 0x7fffu + ((v.u >> 16) & 1u);
  return (u16)(r >> 16);
}

__device__ __forceinline__ void async_cp16(const void* g, void* l) {
  // global -> LDS direct, 16B/lane. LDS dest is wave-uniform base + lane*16.
  __builtin_amdgcn_global_load_lds((const __attribute__((address_space(1))) void*)g,
                                   (__attribute__((address_space(3))) void*)l,
                                   16, 0, 0);
}

__device__ __forceinline__ void barrier_fence() {
  asm volatile("" ::: "memory");
  __builtin_amdgcn_s_barrier();
  asm volatile("" ::: "memory");
}

// ---- K1: fp32->bf16 transpose-convert.  src [E][R][C] f32 -> dst [E][C][R] bf16 ----
// In-side: pack 2 bf16 -> ds_write_b32 (stride-70 keeps both phases conflict-free).
__global__ __launch_bounds__(256) void transpose_cvt64(const float* __restrict__ src,
                                                       u16* __restrict__ dst, int R, int C) {
  int tilesC = C >> 6;
  int per_e = (R >> 6) * tilesC;
  int bid = blockIdx.x;
  int e = bid / per_e, rem = bid % per_e;
  int rt = rem / tilesC, ct = rem % tilesC;
  const float* s = src + (size_t)e * R * C;
  u16* d = dst + (size_t)e * R * C;
  __shared__ u16 tile[64][70];                 // pad 70: bank spread on col reads
  int tid = threadIdx.x;
  int rr = tid >> 4;                           // 0..15
  int c4 = (tid & 15) << 2;                    // 0,4,..60
#pragma unroll
  for (int i = 0; i < 4; ++i) {
    int r = rr + i * 16;
    float4 v = *(const float4*)(s + (size_t)(rt*64 + r) * C + ct*64 + c4);
    unsigned lo = (unsigned)f2bf(v.x) | ((unsigned)f2bf(v.y) << 16);
    unsigned hi = (unsigned)f2bf(v.z) | ((unsigned)f2bf(v.w) << 16);
    *(unsigned*)&tile[r][c4]     = lo;         // byte = r*140 + 2*c4, 4-aligned
    *(unsigned*)&tile[r][c4 + 2] = hi;
  }
  __syncthreads();
#pragma unroll
  for (int k = 0; k < 2; ++k) {
    int idx = k*256 + tid;
    int c  = idx >> 3;                         // 0..63 output row (C-dim)
    int rc = (idx & 7) << 3;                   // 0,8,..56
    union { u16 u[8]; uint4 v; } pk;
#pragma unroll
    for (int j = 0; j < 8; ++j) pk.u[j] = tile[rc + j][c];
    *(uint4*)(d + (size_t)(ct*64 + c) * R + rt*64 + rc) = pk.v;
  }
}

// ---- K2: router logits + noise, top-2 (fp64 accum to avoid near-tie flips) ----
__global__ __launch_bounds__(256) void router_topk(const float* __restrict__ x,
    const float* __restrict__ rw, const float* __restrict__ rb,
    const float* __restrict__ noise, int* __restrict__ topk) {
  int w = threadIdx.x >> 6, lane = threadIdx.x & 63;
  int t = blockIdx.x * 4 + w;
  const float* xr = x + (size_t)t * DMODEL;
  double acc[NEXP];
#pragma unroll
  for (int e = 0; e < NEXP; ++e) acc[e] = 0.0;
  for (int c = lane; c < DMODEL; c += 64) {
    float xv = xr[c];
#pragma unroll
    for (int e = 0; e < NEXP; ++e) acc[e] += (double)xv * (double)rw[e*DMODEL + c];
  }
#pragma unroll
  for (int e = 0; e < NEXP; ++e) {
#pragma unroll
    for (int off = 32; off > 0; off >>= 1) acc[e] += __shfl_down(acc[e], off, 64);
  }
  if (lane == 0) {
    double best = -1e300, sec = -1e300; int bi = 0, si = 0;
#pragma unroll
    for (int e = 0; e < NEXP; ++e) {
      double v = acc[e] + (double)rb[e] + (double)noise[(size_t)t*NEXP + e] * 0.02;
      if (v > best)     { sec = best; si = bi; best = v; bi = e; }
      else if (v > sec) { sec = v; si = e; }
    }
    topk[2*t] = bi; topk[2*t+1] = si;
  }
}

// ---- K3: per-128-token-chunk routed counts per expert ----
__global__ __launch_bounds__(128) void chunk_count(const int* __restrict__ topk,
                                                   int* __restrict__ ccnt) {
  int tid = threadIdx.x, lane = tid & 63, w = tid >> 6;
  int t = blockIdx.x*128 + tid;
  int i0 = topk[2*t], i1 = topk[2*t+1];
  __shared__ int cnt[2][NEXP];
#pragma unroll
  for (int e = 0; e < NEXP; ++e) {
    unsigned long long bal = __ballot((i0 == e) || (i1 == e));
    if (lane == 0) cnt[w][e] = __popcll(bal);
  }
  __syncthreads();
  if (tid < NEXP) ccnt[blockIdx.x*NEXP + tid] = cnt[0][tid] + cnt[1][tid];
}

// ---- K4: exclusive prefix of chunk counts (tiny) ----
__global__ void chunk_prefix(const int* __restrict__ ccnt, int* __restrict__ cbase) {
  int e = threadIdx.x;
  if (e < NEXP) {
    int run = 0;
    for (int c = 0; c < 128; ++c) { cbase[c*NEXP + e] = run; run += ccnt[c*NEXP + e]; }
  }
}

// ---- K5: capacity acceptance, final expert = max accepted, atomic compaction ----
__global__ __launch_bounds__(128) void assign_compact(const int* __restrict__ topk,
    const int* __restrict__ cbase, int* __restrict__ counts, int* __restrict__ lists,
    int* __restrict__ accept) {
  int chunk = blockIdx.x, tid = threadIdx.x;
  int lane = tid & 63, w = tid >> 6;
  int t = chunk*128 + tid;
  int i0 = topk[2*t], i1 = topk[2*t+1];
  __shared__ int w0cnt[NEXP];
  unsigned long long below = (1ull << lane) - 1ull;
#pragma unroll
  for (int e = 0; e < NEXP; ++e) {
    unsigned long long bal = __ballot((i0 == e) || (i1 == e));
    if (w == 0 && lane == 0) w0cnt[e] = __popcll(bal);
  }
  __syncthreads();
  int fin = -1;
#pragma unroll
  for (int e = 0; e < NEXP; ++e) {
    bool m = (i0 == e) || (i1 == e);
    unsigned long long bal = __ballot(m);
    int rank = cbase[chunk*NEXP + e] + (w ? w0cnt[e] : 0) + __popcll(bal & below);
    if (m && rank < CAPACITY) fin = e;    // ascending e -> ends at max accepted
  }
  accept[t] = (fin >= 0) ? 1 : 0;
#pragma unroll
  for (int e = 0; e < NEXP; ++e) {
    bool m = (fin == e);
    unsigned long long bal = __ballot(m);
    int c = __popcll(bal);
    if (c) {
      int leader = __ffsll((unsigned long long)bal) - 1;
      int base = 0;
      if (lane == leader) base = atomicAdd(&counts[e], c);
      base = __shfl(base, leader, 64);
      if (m) lists[e*CAP_PAD + base + __popcll(bal & below)] = t;
    }
  }
}

// ---- K6: padded counts (256-granular for 256-row M-tiles) + compact offsets ----
__global__ void calc_offsets(const int* __restrict__ counts, int* __restrict__ offs,
                             int* __restrict__ pcnt) {
  if (threadIdx.x == 0) {
    int run = 0;
    for (int e = 0; e < NEXP; ++e) {
      offs[e] = run;
      int pc = ((counts[e] + 255) >> 8) << 8;
      pcnt[e] = pc;
      run += pc;
    }
    offs[NEXP] = run;
  }
}

// ---- K6b: zero only dropped-token output rows (replaces 67 MB memset) ----
__global__ __launch_bounds__(256) void zero_dropped(const int* __restrict__ accept,
                                                    float* __restrict__ out) {
  int lane = threadIdx.x & 63, w = threadIdx.x >> 6;
  for (int tok = blockIdx.x*4 + w; tok < T_TOK; tok += gridDim.x*4) {
    if (!accept[tok]) {
      float4 z = make_float4(0.f, 0.f, 0.f, 0.f);
      float4* p = (float4*)(out + (size_t)tok * DMODEL);
#pragma unroll
      for (int i = 0; i < 4; ++i) p[lane + i*64] = z;
    }
  }
}

// ---- K7: gather x rows -> bf16 compact per-expert regions (grid-stride) ----
__global__ __launch_bounds__(128) void gather_x(const float* __restrict__ x,
    const int* __restrict__ lists, const int* __restrict__ counts,
    const int* __restrict__ offs, const int* __restrict__ pcnt, u16* __restrict__ xg) {
  int tid = threadIdx.x;
  for (int idx = blockIdx.x; idx < NEXP*CAP_PAD; idx += gridDim.x) {
    int e = idx / CAP_PAD, r = idx % CAP_PAD;
    if (r >= pcnt[e]) continue;
    unsigned long long* dst = (unsigned long long*)(xg + (size_t)(offs[e] + r) * DMODEL);
    if (r < counts[e]) {
      const float4* src = (const float4*)(x + (size_t)lists[e*CAP_PAD + r] * DMODEL);
#pragma unroll
      for (int i = 0; i < 2; ++i) {
        float4 v = src[tid + i*128];
        unsigned long long pk = (unsigned long long)f2bf(v.x)
                              | ((unsigned long long)f2bf(v.y) << 16)
                              | ((unsigned long long)f2bf(v.z) << 32)
                              | ((unsigned long long)f2bf(v.w) << 48);
        dst[tid + i*128] = pk;
      }
    } else {
#pragma unroll
      for (int i = 0; i < 2; ++i) dst[tid + i*128] = 0ull;
    }
  }
}

// ==================== 256x256 8-wave phase-pipelined GEMM ====================
// T2 swizzle: logical LDS byte (r*128 + cb) lives at r*128 + (cb ^ ((r&7)<<4)).
// Staged via pre-swizzled GLOBAL source, read with the same XOR (rule 21).
// Grid: 3D (x=nt fastest, y=mt, z=e) — interleaves experts across XCDs for
// load balance (R2 lesson: expert-per-XCD chunking halves occupancy on skewed
// counts); consecutive nt blocks share the A panel for L2 reuse.

template<int S>  // row stride in elements (== K)
__device__ __forceinline__ void stage_half(const u16* __restrict__ g, int row0, int k0,
                                           u16* tile, int half, int tid) {
  int wid  = tid >> 6;
  int rloc = tid >> 3;                       // 0..63 row within this 64-row chunk
  int cb   = (tid & 7) << 4;                 // byte col 0..112 step 16
  int scb  = cb ^ ((rloc & 7) << 4);         // pre-swizzled source col (r&7 == rloc&7)
#pragma unroll
  for (int j = 0; j < 2; ++j) {
    int r = half*128 + j*64 + rloc;
    const u16* src = g + (size_t)(row0 + r) * S + k0 + (scb >> 1);
    u16* dst = tile + half*8192 + j*4096 + wid*512;   // u16 units; wave-uniform
    async_cp16(src, dst);
  }
}

__device__ __forceinline__ bf16x8 ldsfrag(const u16* tile, int r, int cb) {
  int a = r*128 + (cb ^ ((r & 7) << 4));     // byte offset, 16B aligned
  return *(const bf16x8*)((const char*)tile + a);
}

// EPI 0: h = gelu(xg@w1+b1) -> bf16 Hout.  EPI 1: out = h@w2+b2 -> f32 scatter.
template<int KELEM, int NTOT, int EPI>
__global__ __launch_bounds__(512, 2) void ffn_gemm8(
    const u16* __restrict__ Abase, const u16* __restrict__ Btall,
    const float* __restrict__ bias,
    const int* __restrict__ offs, const int* __restrict__ pcnt,
    const int* __restrict__ counts, const int* __restrict__ lists,
    u16* __restrict__ Hout, float* __restrict__ Fout) {
  constexpr int NKT = KELEM / 64;
  int e = blockIdx.z, mt = blockIdx.y, nt = blockIdx.x;
  int pc = pcnt[e];
  int m0 = mt * 256;
  if (m0 >= pc) return;                       // uniform: before any barrier
  int n0 = nt * 256;
  int tid = threadIdx.x, lane = tid & 63, wid = tid >> 6;
  int wm = wid >> 2, wn = wid & 3;            // 2 x 4 waves; per-wave 128x64 output
  const u16* A = Abase + (size_t)offs[e] * KELEM;
  const u16* B = Btall + (size_t)e * NTOT * KELEM;
  __shared__ __align__(16) u16 lds[2][2][16384];  // [buf][A,B][32KB] = 128 KiB

  // Prologue: t0 fully into buf0; t1.B into buf1. 12 loads/thread in flight.
  stage_half<KELEM>(A, m0, 0,  (u16*)lds[0][0], 0, tid);
  stage_half<KELEM>(A, m0, 0,  (u16*)lds[0][0], 1, tid);
  stage_half<KELEM>(B, n0, 0,  (u16*)lds[0][1], 0, tid);
  stage_half<KELEM>(B, n0, 0,  (u16*)lds[0][1], 1, tid);
  stage_half<KELEM>(B, n0, 64, (u16*)lds[1][1], 0, tid);
  stage_half<KELEM>(B, n0, 64, (u16*)lds[1][1], 1, tid);
  asm volatile("s_waitcnt vmcnt(4)" ::: "memory");   // t0's 8 loads done; t1.B in flight
  barrier_fence();

  int frow = lane & 15;
  int fk   = (lane >> 4) << 4;                // k byte base within 64-col tile
  f32x4 acc[8][4] = {};

#pragma unroll 2
  for (int t = 0; t < NKT; ++t) {
    int cur = t & 1;
    u16* As_ = (u16*)lds[cur][0];
    u16* Bs_ = (u16*)lds[cur][1];
    u16* An_ = (u16*)lds[cur ^ 1][0];
    bf16x8 a[4][2], bb[2][2][2];

    // ---- phase 0: read A-low frags + B-low frags; stage t+1.A half0; MFMA Q00 ----
#pragma unroll
    for (int f = 0; f < 4; ++f)
#pragma unroll
      for (int kk = 0; kk < 2; ++kk)
        a[f][kk] = ldsfrag(As_, wm*128 + f*16 + frow, kk*64 + fk);
#pragma unroll
    for (int f = 0; f < 2; ++f)
#pragma unroll
      for (int kk = 0; kk < 2; ++kk)
        bb[0][f][kk] = ldsfrag(Bs_, wn*64 + f*16 + frow, kk*64 + fk);
    if (t + 1 < NKT) stage_half<KELEM>(A, m0, (t+1)*64, An_, 0, tid);
    barrier_fence();
    __builtin_amdgcn_s_setprio(1);
#pragma unroll
    for (int f = 0; f < 4; ++f)
#pragma unroll
      for (int g = 0; g < 2; ++g)
#pragma unroll
        for (int kk = 0; kk < 2; ++kk)
          acc[f][g] = __builtin_amdgcn_mfma_f32_16x16x32_bf16(a[f][kk], bb[0][g][kk], acc[f][g], 0, 0, 0);
    __builtin_amdgcn_s_setprio(0);
    barrier_fence();

    // ---- phase 1: read B-high frags; stage t+1.A half1; MFMA Q01 ----
#pragma unroll
    for (int f = 0; f < 2; ++f)
#pragma unroll
      for (int kk = 0; kk < 2; ++kk)
        bb[1][f][kk] = ldsfrag(Bs_, wn*64 + (2+f)*16 + frow, kk*64 + fk);
    if (t + 1 < NKT) stage_half<KELEM>(A, m0, (t+1)*64, An_, 1, tid);
    barrier_fence();
    __builtin_amdgcn_s_setprio(1);
#pragma unroll
    for (int f = 0; f < 4; ++f)
#pragma unroll
      for (int g = 0; g < 2; ++g)
#pragma unroll
        for (int kk = 0; kk < 2; ++kk)
          acc[f][2+g] = __builtin_amdgcn_mfma_f32_16x16x32_bf16(a[f][kk], bb[1][g][kk], acc[f][2+g], 0, 0, 0);
    __builtin_amdgcn_s_setprio(0);
    barrier_fence();

    // ---- phase 2: read A-high frags; stage t+2.B half0 into cur.B; MFMA Q10 ----
#pragma unroll
    for (int f = 0; f < 4; ++f)
#pragma unroll
      for (int kk = 0; kk < 2; ++kk)
        a[f][kk] = ldsfrag(As_, wm*128 + 64 + f*16 + frow, kk*64 + fk);
    if (t + 2 < NKT) stage_half<KELEM>(B, n0, (t+2)*64, Bs_, 0, tid);
    barrier_fence();
    __builtin_amdgcn_s_setprio(1);
#pragma unroll
    for (int f = 0; f < 4; ++f)
#pragma unroll
      for (int g = 0; g < 2; ++g)
#pragma unroll
        for (int kk = 0; kk < 2; ++kk)
          acc[4+f][g] = __builtin_amdgcn_mfma_f32_16x16x32_bf16(a[f][kk], bb[0][g][kk], acc[4+f][g], 0, 0, 0);
    __builtin_amdgcn_s_setprio(0);
    barrier_fence();

    // ---- phase 3: stage t+2.B half1; MFMA Q11; counted boundary vmcnt; barrier ----
    if (t + 2 < NKT) stage_half<KELEM>(B, n0, (t+2)*64, Bs_, 1, tid);
    barrier_fence();
    __builtin_amdgcn_s_setprio(1);
#pragma unroll
    for (int f = 0; f < 4; ++f)
#pragma unroll
      for (int g = 0; g < 2; ++g)
#pragma unroll
        for (int kk = 0; kk < 2; ++kk)
          acc[4+f][2+g] = __builtin_amdgcn_mfma_f32_16x16x32_bf16(a[f][kk], bb[1][g][kk], acc[4+f][2+g], 0, 0, 0);
    __builtin_amdgcn_s_setprio(0);
    // Boundary wait for tile t+1: oldest 8 of 12 in-flight loads are t+1's 4 halves.
    if (t + 2 < NKT)      asm volatile("s_waitcnt vmcnt(4)" ::: "memory");
    else if (t + 1 < NKT) asm volatile("s_waitcnt vmcnt(0)" ::: "memory");  // epilogue drain
    barrier_fence();
  }

  // ---- epilogue ----
  if constexpr (EPI == 0) {
    // One-drain repack: full 128x64 wave tile -> private 16 KB LDS (T2-style XOR
    // swizzle; verified <=2-way per 16-lane phase), ONE lgkmcnt(0), then 16x
    // ds_read_b128 + 16B stores. All 128 erff chains issue with full ILP.
    const float* be = bias + e * NTOT;
    u16* H = Hout + (size_t)offs[e] * NTOT;
    char* mybuf = (char*)lds + wid * 16384;   // 16 KB per wave, 8 waves = 128 KB
    float bv[4];
#pragma unroll
    for (int g = 0; g < 4; ++g) bv[g] = be[n0 + wn*64 + g*16 + frow];
    int r4 = (lane >> 4) * 4;
#pragma unroll
    for (int f = 0; f < 8; ++f)
#pragma unroll
      for (int g = 0; g < 4; ++g)
#pragma unroll
        for (int r = 0; r < 4; ++r) {
          float v = acc[f][g][r] + bv[g];
          float gl = 0.5f * v * (1.0f + erff(v * 0.70710678118654752f));  // exact gelu
          int rr = f*16 + r4 + r;
          int cb = (g*16 + frow) * 2;
          *(u16*)(mybuf + rr*128 + (cb ^ ((rr & 7) << 4))) = f2bf(gl);
        }
    asm volatile("s_waitcnt lgkmcnt(0)" ::: "memory");   // single wave-local drain
#pragma unroll
    for (int rb = 0; rb < 8; ++rb)
#pragma unroll
      for (int kk = 0; kk < 2; ++kk) {
        int rr = rb*16 + frow;
        int c8 = kk*4 + (lane >> 4);
        bf16x8 vv = *(const bf16x8*)(mybuf + rr*128 + ((c8*16) ^ ((rr & 7) << 4)));
        *(bf16x8*)(H + (size_t)(m0 + wm*128 + rr) * NTOT + n0 + wn*64 + c8*8) = vv;
      }
  } else {
    // Vectorized scatter (kept from R4, measured +48 us): repack each wave's
    // 16x64 f32 sub-tile through private LDS, then 4x f32x4 stores per token row.
    int cnt = counts[e];
    const float* be = bias + e * NTOT;
    const int* le = lists + e * CAP_PAD;
    float* mybuf = (float*)((u16*)lds + wid * 2304);   // 16*68=1088 f32, pad 1152 f32
    float bv[4];
#pragma unroll
    for (int g = 0; g < 4; ++g) bv[g] = be[n0 + wn*64 + g*16 + frow];
    int r4 = (lane >> 4) * 4;
#pragma unroll
    for (int f = 0; f < 8; ++f) {
#pragma unroll
      for (int g = 0; g < 4; ++g)
#pragma unroll
        for (int r = 0; r < 4; ++r)
          mybuf[(r4 + r) * 68 + g*16 + frow] = acc[f][g][r] + bv[g];
      asm volatile("s_waitcnt lgkmcnt(0)" ::: "memory");   // wave-local write->read
      int row = lane >> 2, cg = lane & 3;                  // 16 rows x 4 col-groups
      int grow = m0 + wm*128 + f*16 + row;
      if (grow < cnt) {
        int tk = le[grow];
        float* po = Fout + (size_t)tk * DMODEL + n0 + wn*64 + cg*16;
        const float* pb = mybuf + row*68 + cg*16;
#pragma unroll
        for (int j = 0; j < 4; ++j)
          *(f32x4*)(po + j*4) = *(const f32x4*)(pb + j*4);
      }
      asm volatile("s_waitcnt lgkmcnt(0)" ::: "memory");   // reads done before next f
    }
  }
}

extern "C" void kernel_launch(void* const* d_in, const int* in_sizes, int n_in,
                              void* d_out, int out_size, void* d_ws, size_t ws_size,
                              hipStream_t stream) {
  const float* x     = (const float*)d_in[0];
  const float* noise = (const float*)d_in[1];
  const float* rw    = (const float*)d_in[2];
  const float* rb    = (const float*)d_in[3];
  const float* w1    = (const float*)d_in[4];
  const float* b1    = (const float*)d_in[5];
  const float* w2    = (const float*)d_in[6];
  const float* b2    = (const float*)d_in[7];
  float* out = (float*)d_out;
  char* ws = (char*)d_ws;

  u16* w1t   = (u16*)(ws + W1T_OFF);
  u16* w2t   = (u16*)(ws + W2T_OFF);
  u16* xg    = (u16*)(ws + XG_OFF);
  u16* hbuf  = (u16*)(ws + H_OFF);
  int* topk  = (int*)(ws + TOPK_OFF);
  int* ccnt  = (int*)(ws + CCNT_OFF);
  int* cbase = (int*)(ws + CBASE_OFF);
  int* lists = (int*)(ws + LISTS_OFF);
  int* cnts  = (int*)(ws + CNT_OFF);
  int* offs  = (int*)(ws + OFFS_OFF);
  int* pcnt  = (int*)(ws + PCNT_OFF);
  int* accfl = (int*)(ws + ACC_OFF);

  // counts must start at zero (out zeroing handled by zero_dropped per-run)
  hipMemsetAsync(cnts, 0, NEXP * sizeof(int), stream);

  transpose_cvt64<<<NEXP*(DMODEL/64)*(DFF/64), 256, 0, stream>>>(w1, w1t, DMODEL, DFF);
  transpose_cvt64<<<NEXP*(DFF/64)*(DMODEL/64), 256, 0, stream>>>(w2, w2t, DFF, DMODEL);
  router_topk<<<T_TOK/4, 256, 0, stream>>>(x, rw, rb, noise, topk);
  chunk_count<<<128, 128, 0, stream>>>(topk, ccnt);
  chunk_prefix<<<1, 64, 0, stream>>>(ccnt, cbase);
  assign_compact<<<128, 128, 0, stream>>>(topk, cbase, cnts, lists, accfl);
  calc_offsets<<<1, 64, 0, stream>>>(cnts, offs, pcnt);
  zero_dropped<<<512, 256, 0, stream>>>(accfl, out);
  gather_x<<<4096, 128, 0, stream>>>(x, lists, cnts, offs, pcnt, xg);
  ffn_gemm8<DMODEL, DFF, 0><<<dim3(DFF/256, CAP_PAD/256, NEXP), 512, 0, stream>>>(
      xg, w1t, b1, offs, pcnt, cnts, lists, hbuf, nullptr);
  ffn_gemm8<DFF, DMODEL, 1><<<dim3(DMODEL/256, CAP_PAD/256, NEXP), 512, 0, stream>>>(
      hbuf, w2t, b2, offs, pcnt, cnts, lists, nullptr, out);
}